// Round 12
// baseline (580.984 us; speedup 1.0000x reference)
//
#include <hip/hip_runtime.h>

// ---------------- problem constants ----------------
#define N_WORDS 16384
#define MAXL    16
#define VOCABSZ 128
#define EMBD    64
#define HID     256
#define GATES   1024        // 4*HID
#define AROW    264         // A row stride in shorts (h only: 256 + 8 pad)
#define M_TILE  32          // words per workgroup
#define NT      512         // word tiles (N_WORDS / M_TILE)

typedef __attribute__((ext_vector_type(8))) short bf16x8;  // 8 bf16 = 4 VGPRs
typedef __attribute__((ext_vector_type(4))) float f32x4;
typedef __attribute__((ext_vector_type(2))) float f32x2;
typedef __attribute__((ext_vector_type(4))) int   i32x4;

// ---------------- workspace layout (bytes) ----------------
// wsw : swizzled Whh weights, A-fragment order: [dir][R 0..63][kk 0..7][lane][8 bf16]
// xg  : per-char gate table: [dir][char][4*unit+type] = b_ih+b_hh + emb[c]@Wih^T (fp32)
#define OFF_WSW   0ul          // 2*64*8*64*16 = 1048576
#define OFF_XG    1048576ul    // 2*128*1024*4 = 1048576
#define OFF_SORT  2097152ul    // 16384 ints = 65536
// cell state lives in LDS -- no global c buffer

__device__ inline short tobf(float f) {           // fp32 -> bf16 RNE
  unsigned u = __float_as_uint(f);
  unsigned r = (u + 0x7fffu + ((u >> 16) & 1u)) >> 16;
  return (short)r;
}
// raw transcendental units via inline asm
__device__ inline float aexp2(float x) { float r; asm("v_exp_f32 %0, %1" : "=v"(r) : "v"(x)); return r; }
__device__ inline float arcp(float x)  { float r; asm("v_rcp_f32 %0, %1" : "=v"(r) : "v"(x)); return r; }
__device__ inline float fsig(float x)   { return arcp(1.0f + aexp2(x * -1.4426950408889634f)); }
__device__ inline float ftanhf(float x) { return 1.0f - 2.0f * arcp(1.0f + aexp2(x * 2.8853900817779268f)); }

// ---------------- fused prep (1 launch) -------------------------------------
// blocks 0..255    : Whh swizzle into MFMA A-fragment layout (kk 0..7 only)
// blocks 256..1279 : xg char-gate table (fp32-exact x contribution + bias)
// block  1280      : single-block length-bucket sort (bin order arbitrary)
__global__ void prep_all(const float* __restrict__ Wihf, const float* __restrict__ Whhf,
                         const float* __restrict__ Wihb, const float* __restrict__ Whhb,
                         const float* __restrict__ emb,
                         const float* __restrict__ bihf, const float* __restrict__ bhhf,
                         const float* __restrict__ bihb, const float* __restrict__ bhhb,
                         const int* __restrict__ lengths,
                         short* __restrict__ wsw, float* __restrict__ xg,
                         int* __restrict__ sorted) {
  __shared__ int hist[16], base[16], cnt[16];
  int blk = blockIdx.x;
  if (blk < 256) {            // Whh swizzle: 2*64*8*64 = 65536 fragments
    int id = blk * 256 + threadIdx.x;
    int d    = id >> 15;
    int r    = id & 32767;
    int R    = r >> 9;
    int r2   = r & 511;
    int kk   = r2 >> 6;
    int lane = r2 & 63;
    int m    = lane & 15;
    int unit = R * 4 + (m >> 2);
    int ty   = m & 3;
    int g    = ty * 256 + unit;
    int kb   = kk * 32 + (lane >> 4) * 8;
    const float* Whh = d ? Whhb : Whhf;
    bf16x8 v;
#pragma unroll
    for (int j = 0; j < 8; ++j) v[j] = tobf(Whh[g * HID + kb + j]);
    ((bf16x8*)wsw)[id] = v;
  } else if (blk < 1280) {    // xg table: 2*128*1024 entries, fp32-exact
    int id = (blk - 256) * 256 + threadIdx.x;   // 0..262143
    int d  = id >> 17;
    int r  = id & 131071;
    int c  = r >> 10;
    int n  = r & 1023;                          // interleaved 4*unit+type
    int u  = n >> 2, ty = n & 3;
    int g  = ty * 256 + u;
    const float* Wih = d ? Wihb : Wihf;
    const float* bi  = d ? bihb : bihf;
    const float* bh  = d ? bhhb : bhhf;
    const f32x4* e4 = (const f32x4*)(emb + c * EMBD);
    const f32x4* w4 = (const f32x4*)(Wih + g * EMBD);
    f32x4 a = {0.f, 0.f, 0.f, 0.f};
#pragma unroll
    for (int i = 0; i < 16; ++i) a += e4[i] * w4[i];
    xg[id] = bi[g] + bh[g] + a[0] + a[1] + a[2] + a[3];
  } else {                    // length-bucket sort, 256 threads
    int tid = threadIdx.x;
    if (tid < 16) { hist[tid] = 0; cnt[tid] = 0; }
    __syncthreads();
    for (int i = tid; i < N_WORDS; i += 256)
      atomicAdd(&hist[lengths[i] - 1], 1);
    __syncthreads();
    if (tid == 0) {
      int s = 0;
      for (int b = 0; b < 16; ++b) { base[b] = s; s += hist[b]; }
    }
    __syncthreads();
    for (int i = tid; i < N_WORDS; i += 256) {
      int b = lengths[i] - 1;
      int p = base[b] + atomicAdd(&cnt[b], 1);
      sorted[p] = i;
    }
  }
}

// ---------------- main fused BiLSTM kernel ----------------
// R12 = R11 with the compile fix (hx_ declared BEFORE the wtile lambda).
//  (1) 4 independent MFMA chains (kk lo/hi x 2ct) -- R10's 2-chain version
//      halved pipe efficiency (MfmaUtil 20.6->13.4);
//  (2) xg char-gate loads ping-pong prefetched one tile ahead (scattered L2
//      gathers get a full tile of cover); cross-step via ccN scalar bases;
//  (3) 3 BLOCKS/CU: LDS 52 KB, weight single-buffered (-32 VGPR) to fit the
//      168-reg/wave cap at 3 waves/SIMD -- per-wave weight-load stalls are
//      absorbed by the +50% TLP (m114 overlap), which R2..R9 showed is the
//      actual bottleneck (all pipes <30% at 2 waves/SIMD, latency-bound).
// Layout (R8-proven): lane owns unit 64wv+4rt+quad, word ct*16+colc;
// acc regs = i,f,g,o. Cell state: LDS f32x2 per (wv,rt,lane).
// Barriers are lgkm-only (no global data crosses waves) so vmem prefetch
// stays in flight across steps.
__global__ __launch_bounds__(256, 3) void lstm_main(
    const int* __restrict__ char_ids, const int* __restrict__ lengths,
    const short* __restrict__ wsw, const float* __restrict__ xg,
    const int* __restrict__ sorted, float* __restrict__ out) {
  __shared__ __align__(16) short A[M_TILE * AROW];   // [word][h(256)+pad] 16.9 KB
  __shared__ __align__(16) int   charl[M_TILE * 16]; // 2 KB
  __shared__ __align__(8)  f32x2 c4[4 * 16 * 64];    // [wv][rt][lane] cell, 32 KB
  __shared__ int lenl[M_TILE];
  __shared__ int swl[M_TILE];

  const int tid  = threadIdx.x;
  const int lane = tid & 63;
  const int wv   = tid >> 6;            // 0..3
  const int quad = lane >> 4;
  const int colc = lane & 15;
  const int pb   = blockIdx.x;
  const int dir  = pb & 1;
  const int qb   = pb >> 1;
  const int tile = (qb & 1) ? (511 - (qb >> 1)) : (qb >> 1);

  if (tid < M_TILE) {
    int sw = sorted[tile * M_TILE + tid];
    swl[tid]  = sw;
    lenl[tid] = lengths[sw];
  }
  for (int i = tid; i < M_TILE * AROW / 2; i += 256) ((int*)A)[i] = 0;     // h=0
  for (int i = tid; i < 4 * 16 * 64; i += 256) c4[i] = (f32x2){0.f, 0.f};  // c=0
  __syncthreads();

  if (tid < 128) { // char ids for the tile (via sorted ids): 32 words x 16
    int w = tid >> 2, ch = tid & 3;
    ((i32x4*)charl)[tid] = ((const i32x4*)(char_ids + swl[w] * 16))[ch];
  }
  int Lmax = lenl[lane & 31];
  for (int o = 32; o; o >>= 1) { int v = __shfl_xor(Lmax, o, 64); Lmax = Lmax > v ? Lmax : v; }
  __syncthreads();  // charl ready

  // step-invariant lane constants (word dimension, per col-tile ct)
  int lenw0, lenw1, hadrb0, hadrb1, oadr0, oadr1;
  {
    int wl0 = colc, wl1 = 16 + colc;
    lenw0 = lenl[wl0];                  lenw1 = lenl[wl1];
    hadrb0 = wl0 * AROW + 64 * wv + quad;
    hadrb1 = wl1 * AROW + 64 * wv + quad;
    oadr0 = swl[wl0] * 512 + dir * 256 + 64 * wv + quad;
    oadr1 = swl[wl1] * 512 + dir * 256 + 64 * wv + quad;
  }
  const short* wp  = wsw + ((size_t)(dir * 64 + wv * 16)) * 4096 + lane * 8;
  const float* xga = xg + dir * (VOCABSZ * GATES);
  f32x2* cptr = c4 + wv * (16 * 64) + lane;   // + rt*64

  // xg row base for (word ct, step tt); clamped pos for dead steps is harmless
  auto ccof = [&](int tt, int len, int wl) -> int {
    int pos = (dir == 0) ? tt : (len - 1 - tt);
    pos = pos < 0 ? 0 : (pos > 15 ? 15 : pos);
    return charl[wl * 16 + pos] * GATES + 256 * wv + 4 * quad;
  };
  int cc0 = ccof(0, lenw0, colc), cc1 = ccof(0, lenw1, 16 + colc);

  __syncthreads();  // zeros visible

  // xg ping-pong buffers; prologue: load rt=0 gates for t=0
  f32x4 xgA0 = *(const f32x4*)(xga + cc0);
  f32x4 xgA1 = *(const f32x4*)(xga + cc1);
  f32x4 xgB0, xgB1;

  bf16x8 hx_[2][8];  // B fragments (declared BEFORE wtile so the lambda captures)

  // weights single-buffered (fits 168-reg cap at 3 waves/SIMD); the per-tile
  // load latency is hidden by the 2 other resident blocks' waves.
  auto wtile = [&](int rt, f32x4 xc0, f32x4 xc1, f32x4& xn0, f32x4& xn1,
                   int nb0, int nb1, int t) {
    bf16x8 wc[8];
#pragma unroll
    for (int kk = 0; kk < 8; ++kk) wc[kk] = *(const bf16x8*)(wp + (rt * 8 + kk) * 512);
    // prefetch NEXT tile's xg (scattered gather -> full tile of cover); issued
    // after wc so the MFMA's vmcnt wait leaves these in flight
    int rn = (rt + 1) & 15;
    xn0 = *(const f32x4*)(xga + nb0 + 16 * rn);
    xn1 = *(const f32x4*)(xga + nb1 + 16 * rn);
    f32x2 co2 = cptr[rt * 64];                 // LDS c, covered by the MFMA block
    f32x4 aL[2], aH[2];
#pragma unroll
    for (int ct = 0; ct < 2; ++ct) {
      aL[ct] = (f32x4){0.f, 0.f, 0.f, 0.f};
      aH[ct] = (f32x4){0.f, 0.f, 0.f, 0.f};
    }
#pragma unroll
    for (int kk = 0; kk < 4; ++kk)
#pragma unroll
      for (int ct = 0; ct < 2; ++ct) {  // 4 independent MFMA chains (R10 bug fixed)
        aL[ct] = __builtin_amdgcn_mfma_f32_16x16x32_bf16(wc[kk],     hx_[ct][kk],     aL[ct], 0, 0, 0);
        aH[ct] = __builtin_amdgcn_mfma_f32_16x16x32_bf16(wc[kk + 4], hx_[ct][kk + 4], aH[ct], 0, 0, 0);
      }
    f32x2 cnew;
#pragma unroll
    for (int ct = 0; ct < 2; ++ct) {
      f32x4 g4 = aL[ct] + aH[ct] + (ct ? xc1 : xc0);
      // lane-private epilogue: g4 = i,f,g,o of (unit 64wv+4rt+quad, word ct*16+colc)
      // always-write: masked words' h/c are don't-care (bounded, never output)
      float ig = fsig(g4[0]);
      float fg = fsig(g4[1]);
      float gg = ftanhf(g4[2]);
      float og = fsig(g4[3]);
      float c2 = fg * co2[ct] + ig * gg;
      float h2 = og * ftanhf(c2);
      cnew[ct] = c2;
      A[(ct ? hadrb1 : hadrb0) + 4 * rt] = tobf(h2);
      if (t == (ct ? lenw1 : lenw0) - 1)
        out[(ct ? oadr1 : oadr0) + 4 * rt] = h2;  // final h in fp32
    }
    cptr[rt * 64] = cnew;   // one ds_write_b64 (own slice, no hazard)
  };

#pragma unroll 1
  for (int t = 0; t < Lmax; ++t) {
#pragma unroll
    for (int ct = 0; ct < 2; ++ct)
#pragma unroll
      for (int kk = 0; kk < 8; ++kk)
        hx_[ct][kk] = *(const bf16x8*)(A + (ct * 16 + colc) * AROW + kk * 32 + quad * 8);
    // next step's xg bases (charl read-only; needed for rt=15's cross-step prefetch)
    int ccN0 = ccof(t + 1, lenw0, colc);
    int ccN1 = ccof(t + 1, lenw1, 16 + colc);

    // lgkm-only barrier: all waves snapshotted h; vmem prefetch stays in flight
    asm volatile("s_waitcnt lgkmcnt(0)\n\ts_barrier" ::: "memory");

#pragma unroll 1
    for (int rt2 = 0; rt2 < 14; rt2 += 2) {
      wtile(rt2,     xgA0, xgA1, xgB0, xgB1, cc0, cc1, t);
      wtile(rt2 + 1, xgB0, xgB1, xgA0, xgA1, cc0, cc1, t);
    }
    wtile(14, xgA0, xgA1, xgB0, xgB1, cc0,  cc1,  t);
    wtile(15, xgB0, xgB1, xgA0, xgA1, ccN0, ccN1, t);   // prefetch next step's rt0
    cc0 = ccN0; cc1 = ccN1;

    // lgkm-only barrier: h/c LDS writes visible; vmem prefetch uninterrupted
    asm volatile("s_waitcnt lgkmcnt(0)\n\ts_barrier" ::: "memory");
  }
}

// ---------------- launch ----------------
extern "C" void kernel_launch(void* const* d_in, const int* in_sizes, int n_in,
                              void* d_out, int out_size, void* d_ws, size_t ws_size,
                              hipStream_t stream) {
  const int*   char_ids = (const int*)d_in[0];
  const int*   lengths  = (const int*)d_in[1];
  const float* emb      = (const float*)d_in[2];
  const float* Wihf     = (const float*)d_in[3];
  const float* Whhf     = (const float*)d_in[4];
  const float* bihf     = (const float*)d_in[5];
  const float* bhhf     = (const float*)d_in[6];
  const float* Wihb     = (const float*)d_in[7];
  const float* Whhb     = (const float*)d_in[8];
  const float* bihb     = (const float*)d_in[9];
  const float* bhhb     = (const float*)d_in[10];

  char* ws = (char*)d_ws;
  short* wsw   = (short*)(ws + OFF_WSW);
  float* xg    = (float*)(ws + OFF_XG);
  int*   sortd = (int*)(ws + OFF_SORT);

  prep_all<<<1281, 256, 0, stream>>>(Wihf, Whhf, Wihb, Whhb, emb,
                                     bihf, bhhf, bihb, bhhb, lengths,
                                     wsw, xg, sortd);
  lstm_main<<<1024, 256, 0, stream>>>(char_ids, lengths, wsw, xg, sortd,
                                      (float*)d_out);
}

// Round 14
// 501.293 us; speedup vs baseline: 1.1590x; 1.1590x over previous
//
#include <hip/hip_runtime.h>

// ---------------- problem constants ----------------
#define N_WORDS 16384
#define MAXL    16
#define VOCABSZ 128
#define EMBD    64
#define HID     256
#define GATES   1024        // 4*HID
#define AROW    264         // A row stride in shorts (h only: 256 + 8 pad)
#define M_TILE  32          // words per workgroup
#define NT      512         // word tiles (N_WORDS / M_TILE)

typedef __attribute__((ext_vector_type(8))) short bf16x8;  // 8 bf16 = 4 VGPRs
typedef __attribute__((ext_vector_type(4))) float f32x4;
typedef __attribute__((ext_vector_type(2))) float f32x2;
typedef __attribute__((ext_vector_type(4))) int   i32x4;

// ---------------- workspace layout (bytes) ----------------
// wsw : swizzled Whh weights, A-fragment order: [dir][R 0..63][kk 0..7][lane][8 bf16]
// xg  : per-char gate table: [dir][char][4*unit+type] = b_ih+b_hh + emb[c]@Wih^T (fp32)
#define OFF_WSW   0ul          // 2*64*8*64*16 = 1048576
#define OFF_XG    1048576ul    // 2*128*1024*4 = 1048576
#define OFF_SORT  2097152ul    // 16384 ints = 65536
// cell state lives in LDS -- no global c buffer

__device__ inline short tobf(float f) {           // fp32 -> bf16 RNE
  unsigned u = __float_as_uint(f);
  unsigned r = (u + 0x7fffu + ((u >> 16) & 1u)) >> 16;
  return (short)r;
}
// raw transcendental units via inline asm
__device__ inline float aexp2(float x) { float r; asm("v_exp_f32 %0, %1" : "=v"(r) : "v"(x)); return r; }
__device__ inline float arcp(float x)  { float r; asm("v_rcp_f32 %0, %1" : "=v"(r) : "v"(x)); return r; }
__device__ inline float fsig(float x)   { return arcp(1.0f + aexp2(x * -1.4426950408889634f)); }
__device__ inline float ftanhf(float x) { return 1.0f - 2.0f * arcp(1.0f + aexp2(x * 2.8853900817779268f)); }

// ---------------- fused prep (1 launch) -------------------------------------
// blocks 0..255    : Whh swizzle into MFMA A-fragment layout (kk 0..7)
// blocks 256..1279 : xg char-gate table (fp32-exact x contribution + bias)
// block  1280      : single-block length-bucket sort (bin order arbitrary)
__global__ void prep_all(const float* __restrict__ Wihf, const float* __restrict__ Whhf,
                         const float* __restrict__ Wihb, const float* __restrict__ Whhb,
                         const float* __restrict__ emb,
                         const float* __restrict__ bihf, const float* __restrict__ bhhf,
                         const float* __restrict__ bihb, const float* __restrict__ bhhb,
                         const int* __restrict__ lengths,
                         short* __restrict__ wsw, float* __restrict__ xg,
                         int* __restrict__ sorted) {
  __shared__ int hist[16], base[16], cnt[16];
  int blk = blockIdx.x;
  if (blk < 256) {            // Whh swizzle: 2*64*8*64 = 65536 fragments
    int id = blk * 256 + threadIdx.x;
    int d    = id >> 15;
    int r    = id & 32767;
    int R    = r >> 9;
    int r2   = r & 511;
    int kk   = r2 >> 6;
    int lane = r2 & 63;
    int m    = lane & 15;
    int unit = R * 4 + (m >> 2);
    int ty   = m & 3;
    int g    = ty * 256 + unit;
    int kb   = kk * 32 + (lane >> 4) * 8;
    const float* Whh = d ? Whhb : Whhf;
    bf16x8 v;
#pragma unroll
    for (int j = 0; j < 8; ++j) v[j] = tobf(Whh[g * HID + kb + j]);
    ((bf16x8*)wsw)[id] = v;
  } else if (blk < 1280) {    // xg table: 2*128*1024 entries, fp32-exact
    int id = (blk - 256) * 256 + threadIdx.x;   // 0..262143
    int d  = id >> 17;
    int r  = id & 131071;
    int c  = r >> 10;
    int n  = r & 1023;                          // interleaved 4*unit+type
    int u  = n >> 2, ty = n & 3;
    int g  = ty * 256 + u;
    const float* Wih = d ? Wihb : Wihf;
    const float* bi  = d ? bihb : bihf;
    const float* bh  = d ? bhhb : bhhf;
    const f32x4* e4 = (const f32x4*)(emb + c * EMBD);
    const f32x4* w4 = (const f32x4*)(Wih + g * EMBD);
    f32x4 a = {0.f, 0.f, 0.f, 0.f};
#pragma unroll
    for (int i = 0; i < 16; ++i) a += e4[i] * w4[i];
    xg[id] = bi[g] + bh[g] + a[0] + a[1] + a[2] + a[3];
  } else {                    // length-bucket sort, 256 threads
    int tid = threadIdx.x;
    if (tid < 16) { hist[tid] = 0; cnt[tid] = 0; }
    __syncthreads();
    for (int i = tid; i < N_WORDS; i += 256)
      atomicAdd(&hist[lengths[i] - 1], 1);
    __syncthreads();
    if (tid == 0) {
      int s = 0;
      for (int b = 0; b < 16; ++b) { base[b] = s; s += hist[b]; }
    }
    __syncthreads();
    for (int i = tid; i < N_WORDS; i += 256) {
      int b = lengths[i] - 1;
      int p = base[b] + atomicAdd(&cnt[b], 1);
      sorted[p] = i;
    }
  }
}

// ---------------- main fused BiLSTM kernel ----------------
// R14 = R8 frame (362 us, proven clean) + xg table, nothing else:
//  - K 320 -> 256: MFMA -20%, weight stream -20%, no embw gather / x staging;
//  - PING-PONG weights kept (R12 proved single-buffer costs ~12%: per-tile
//    wc-load -> MFMA serialization);
//  - 4 independent MFMA chains (kk 4+4 x 2ct; R10's 2-chain bug halved MfmaUtil);
//  - xg ping-pong prefetch (R12-proven): scattered L2 gathers get a full tile
//    of cover; cross-step via ccN scalar bases;
//  - lgkm-only barriers (R12-proven correct): vmem prefetch survives steps.
// R13 lesson: CU regfile is 512 KB total (128-VGPR cap at 4 waves/SIMD) --
// weight residency is arithmetically impossible; streaming + ping-pong it is.
// Layout (R8-proven): lane owns unit 64wv+4rt+quad, word ct*16+colc;
// acc regs = i,f,g,o. Cell state: LDS f32x2 per (wv,rt,lane). Always-write
// epilogue (masked h/c are bounded don't-cares; out captured at t==len-1).
__global__ __launch_bounds__(256, 2) void lstm_main(
    const int* __restrict__ char_ids, const int* __restrict__ lengths,
    const short* __restrict__ wsw, const float* __restrict__ xg,
    const int* __restrict__ sorted, float* __restrict__ out) {
  __shared__ __align__(16) short A[M_TILE * AROW];   // [word][h(256)+pad] 16.9 KB
  __shared__ __align__(16) int   charl[M_TILE * 16]; // 2 KB
  __shared__ __align__(8)  f32x2 c4[4 * 16 * 64];    // [wv][rt][lane] cell, 32 KB
  __shared__ int lenl[M_TILE];
  __shared__ int swl[M_TILE];

  const int tid  = threadIdx.x;
  const int lane = tid & 63;
  const int wv   = tid >> 6;            // 0..3
  const int quad = lane >> 4;
  const int colc = lane & 15;
  const int pb   = blockIdx.x;
  const int dir  = pb & 1;
  const int qb   = pb >> 1;
  const int tile = (qb & 1) ? (511 - (qb >> 1)) : (qb >> 1);

  if (tid < M_TILE) {
    int sw = sorted[tile * M_TILE + tid];
    swl[tid]  = sw;
    lenl[tid] = lengths[sw];
  }
  for (int i = tid; i < M_TILE * AROW / 2; i += 256) ((int*)A)[i] = 0;     // h=0
  for (int i = tid; i < 4 * 16 * 64; i += 256) c4[i] = (f32x2){0.f, 0.f}; // c=0
  __syncthreads();

  if (tid < 128) { // char ids for the tile (via sorted ids): 32 words x 16
    int w = tid >> 2, ch = tid & 3;
    ((i32x4*)charl)[tid] = ((const i32x4*)(char_ids + swl[w] * 16))[ch];
  }
  int Lmax = lenl[lane & 31];
  for (int o = 32; o; o >>= 1) { int v = __shfl_xor(Lmax, o, 64); Lmax = Lmax > v ? Lmax : v; }
  __syncthreads();  // charl ready

  // step-invariant lane constants (word dimension, per col-tile ct)
  int lenw0, lenw1, hadrb0, hadrb1, oadr0, oadr1;
  {
    int wl0 = colc, wl1 = 16 + colc;
    lenw0 = lenl[wl0];                  lenw1 = lenl[wl1];
    hadrb0 = wl0 * AROW + 64 * wv + quad;
    hadrb1 = wl1 * AROW + 64 * wv + quad;
    oadr0 = swl[wl0] * 512 + dir * 256 + 64 * wv + quad;
    oadr1 = swl[wl1] * 512 + dir * 256 + 64 * wv + quad;
  }
  const short* wp  = wsw + ((size_t)(dir * 64 + wv * 16)) * 4096 + lane * 8;
  const float* xga = xg + dir * (VOCABSZ * GATES);
  f32x2* cptr = c4 + wv * (16 * 64) + lane;   // + rt*64

  // xg row base for (word ct, step tt); clamped pos for dead steps is harmless
  auto ccof = [&](int tt, int len, int wl) -> int {
    int pos = (dir == 0) ? tt : (len - 1 - tt);
    pos = pos < 0 ? 0 : (pos > 15 ? 15 : pos);
    return charl[wl * 16 + pos] * GATES + 256 * wv + 4 * quad;
  };
  int cc0 = ccof(0, lenw0, colc), cc1 = ccof(0, lenw1, 16 + colc);

  __syncthreads();  // zeros visible

  // prologue loads: rt=0 weights + rt=0 xg for t=0
  bf16x8 wA[8], wB[8];
#pragma unroll
  for (int kk = 0; kk < 8; ++kk) wA[kk] = *(const bf16x8*)(wp + kk * 512);
  f32x4 xgA0 = *(const f32x4*)(xga + cc0);
  f32x4 xgA1 = *(const f32x4*)(xga + cc1);
  f32x4 xgB0, xgB1;

  bf16x8 hx_[2][8];  // B fragments (declared BEFORE wtile so the lambda captures)

  auto wtile = [&](int rt, bf16x8 (&wc)[8], bf16x8 (&wn)[8], int pre,
                   f32x4 xc0, f32x4 xc1, f32x4& xn0, f32x4& xn1,
                   int nb0, int nb1, int t) {
    // prefetch next tile's weights (pre=0 at rt=15 warms next step's rt0)
#pragma unroll
    for (int kk = 0; kk < 8; ++kk) wn[kk] = *(const bf16x8*)(wp + (pre * 8 + kk) * 512);
    // prefetch NEXT tile's xg (scattered gather -> full tile of cover)
    int rn = (rt + 1) & 15;
    xn0 = *(const f32x4*)(xga + nb0 + 16 * rn);
    xn1 = *(const f32x4*)(xga + nb1 + 16 * rn);
    f32x2 co2 = cptr[rt * 64];                 // LDS c, covered by the MFMA block
    f32x4 aL[2], aH[2];
#pragma unroll
    for (int ct = 0; ct < 2; ++ct) {
      aL[ct] = (f32x4){0.f, 0.f, 0.f, 0.f};
      aH[ct] = (f32x4){0.f, 0.f, 0.f, 0.f};
    }
#pragma unroll
    for (int kk = 0; kk < 4; ++kk)
#pragma unroll
      for (int ct = 0; ct < 2; ++ct) {  // 4 independent MFMA chains
        aL[ct] = __builtin_amdgcn_mfma_f32_16x16x32_bf16(wc[kk],     hx_[ct][kk],     aL[ct], 0, 0, 0);
        aH[ct] = __builtin_amdgcn_mfma_f32_16x16x32_bf16(wc[kk + 4], hx_[ct][kk + 4], aH[ct], 0, 0, 0);
      }
    f32x2 cnew;
#pragma unroll
    for (int ct = 0; ct < 2; ++ct) {
      f32x4 g4 = aL[ct] + aH[ct] + (ct ? xc1 : xc0);
      // lane-private epilogue: g4 = i,f,g,o of (unit 64wv+4rt+quad, word ct*16+colc)
      // always-write: masked words' h/c are don't-care (bounded, never output)
      float ig = fsig(g4[0]);
      float fg = fsig(g4[1]);
      float gg = ftanhf(g4[2]);
      float og = fsig(g4[3]);
      float c2 = fg * co2[ct] + ig * gg;
      float h2 = og * ftanhf(c2);
      cnew[ct] = c2;
      A[(ct ? hadrb1 : hadrb0) + 4 * rt] = tobf(h2);
      if (t == (ct ? lenw1 : lenw0) - 1)
        out[(ct ? oadr1 : oadr0) + 4 * rt] = h2;  // final h in fp32
    }
    cptr[rt * 64] = cnew;   // one ds_write_b64 (own slice, no hazard)
  };

#pragma unroll 1
  for (int t = 0; t < Lmax; ++t) {
#pragma unroll
    for (int ct = 0; ct < 2; ++ct)
#pragma unroll
      for (int kk = 0; kk < 8; ++kk)
        hx_[ct][kk] = *(const bf16x8*)(A + (ct * 16 + colc) * AROW + kk * 32 + quad * 8);
    // next step's xg bases (charl read-only; for rt=15's cross-step prefetch)
    int ccN0 = ccof(t + 1, lenw0, colc);
    int ccN1 = ccof(t + 1, lenw1, 16 + colc);

    // lgkm-only barrier: all waves snapshotted h; vmem prefetch stays in flight
    asm volatile("s_waitcnt lgkmcnt(0)\n\ts_barrier" ::: "memory");

#pragma unroll 1
    for (int rt2 = 0; rt2 < 14; rt2 += 2) {
      wtile(rt2,     wA, wB, rt2 + 1, xgA0, xgA1, xgB0, xgB1, cc0, cc1, t);
      wtile(rt2 + 1, wB, wA, rt2 + 2, xgB0, xgB1, xgA0, xgA1, cc0, cc1, t);
    }
    wtile(14, wA, wB, 15, xgA0, xgA1, xgB0, xgB1, cc0,  cc1,  t);
    wtile(15, wB, wA, 0,  xgB0, xgB1, xgA0, xgA1, ccN0, ccN1, t);  // next step rt0
    cc0 = ccN0; cc1 = ccN1;

    // lgkm-only barrier: h/c LDS writes visible; vmem prefetch uninterrupted
    asm volatile("s_waitcnt lgkmcnt(0)\n\ts_barrier" ::: "memory");
  }
}

// ---------------- launch ----------------
extern "C" void kernel_launch(void* const* d_in, const int* in_sizes, int n_in,
                              void* d_out, int out_size, void* d_ws, size_t ws_size,
                              hipStream_t stream) {
  const int*   char_ids = (const int*)d_in[0];
  const int*   lengths  = (const int*)d_in[1];
  const float* emb      = (const float*)d_in[2];
  const float* Wihf     = (const float*)d_in[3];
  const float* Whhf     = (const float*)d_in[4];
  const float* bihf     = (const float*)d_in[5];
  const float* bhhf     = (const float*)d_in[6];
  const float* Wihb     = (const float*)d_in[7];
  const float* Whhb     = (const float*)d_in[8];
  const float* bihb     = (const float*)d_in[9];
  const float* bhhb     = (const float*)d_in[10];

  char* ws = (char*)d_ws;
  short* wsw   = (short*)(ws + OFF_WSW);
  float* xg    = (float*)(ws + OFF_XG);
  int*   sortd = (int*)(ws + OFF_SORT);

  prep_all<<<1281, 256, 0, stream>>>(Wihf, Whhf, Wihb, Whhb, emb,
                                     bihf, bhhf, bihb, bhhb, lengths,
                                     wsw, xg, sortd);
  lstm_main<<<1024, 256, 0, stream>>>(char_ids, lengths, wsw, xg, sortd,
                                      (float*)d_out);
}

// Round 15
// 500.608 us; speedup vs baseline: 1.1606x; 1.0014x over previous
//
#include <hip/hip_runtime.h>

// ---------------- problem constants ----------------
#define N_WORDS 16384
#define MAXL    16
#define VOCABSZ 128
#define EMBD    64
#define HID     256
#define GATES   1024        // 4*HID
#define AROW    264         // A row stride in shorts (h only: 256 + 8 pad)
#define M_TILE  32          // words per workgroup
#define NT      512         // word tiles (N_WORDS / M_TILE)

typedef __attribute__((ext_vector_type(8))) short bf16x8;  // 8 bf16 = 4 VGPRs
typedef __attribute__((ext_vector_type(4))) float f32x4;
typedef __attribute__((ext_vector_type(2))) float f32x2;
typedef __attribute__((ext_vector_type(4))) int   i32x4;

// ---------------- workspace layout (bytes) ----------------
// wsw : swizzled Whh weights, A-fragment order: [dir][R 0..63][kk 0..7][lane][8 bf16]
// xg  : per-char gate table: [dir][char][4*unit+type] = b_ih+b_hh + emb[c]@Wih^T (fp32)
#define OFF_WSW   0ul          // 2*64*8*64*16 = 1048576
#define OFF_XG    1048576ul    // 2*128*1024*4 = 1048576
#define OFF_SORT  2097152ul    // 16384 ints = 65536
// cell state lives in LDS -- no global c buffer

__device__ inline short tobf(float f) {           // fp32 -> bf16 RNE
  unsigned u = __float_as_uint(f);
  unsigned r = (u + 0x7fffu + ((u >> 16) & 1u)) >> 16;
  return (short)r;
}
// raw transcendental units via inline asm
__device__ inline float aexp2(float x) { float r; asm("v_exp_f32 %0, %1" : "=v"(r) : "v"(x)); return r; }
__device__ inline float arcp(float x)  { float r; asm("v_rcp_f32 %0, %1" : "=v"(r) : "v"(x)); return r; }
__device__ inline float fsig(float x)   { return arcp(1.0f + aexp2(x * -1.4426950408889634f)); }
__device__ inline float ftanhf(float x) { return 1.0f - 2.0f * arcp(1.0f + aexp2(x * 2.8853900817779268f)); }

// ---------------- fused prep (1 launch) -------------------------------------
// blocks 0..255    : Whh swizzle into MFMA A-fragment layout (kk 0..7)
// blocks 256..1279 : xg char-gate table (fp32-exact x contribution + bias)
// block  1280      : single-block length-bucket sort (bin order arbitrary)
__global__ void prep_all(const float* __restrict__ Wihf, const float* __restrict__ Whhf,
                         const float* __restrict__ Wihb, const float* __restrict__ Whhb,
                         const float* __restrict__ emb,
                         const float* __restrict__ bihf, const float* __restrict__ bhhf,
                         const float* __restrict__ bihb, const float* __restrict__ bhhb,
                         const int* __restrict__ lengths,
                         short* __restrict__ wsw, float* __restrict__ xg,
                         int* __restrict__ sorted) {
  __shared__ int hist[16], base[16], cnt[16];
  int blk = blockIdx.x;
  if (blk < 256) {            // Whh swizzle: 2*64*8*64 = 65536 fragments
    int id = blk * 256 + threadIdx.x;
    int d    = id >> 15;
    int r    = id & 32767;
    int R    = r >> 9;
    int r2   = r & 511;
    int kk   = r2 >> 6;
    int lane = r2 & 63;
    int m    = lane & 15;
    int unit = R * 4 + (m >> 2);
    int ty   = m & 3;
    int g    = ty * 256 + unit;
    int kb   = kk * 32 + (lane >> 4) * 8;
    const float* Whh = d ? Whhb : Whhf;
    bf16x8 v;
#pragma unroll
    for (int j = 0; j < 8; ++j) v[j] = tobf(Whh[g * HID + kb + j]);
    ((bf16x8*)wsw)[id] = v;
  } else if (blk < 1280) {    // xg table: 2*128*1024 entries, fp32-exact
    int id = (blk - 256) * 256 + threadIdx.x;   // 0..262143
    int d  = id >> 17;
    int r  = id & 131071;
    int c  = r >> 10;
    int n  = r & 1023;                          // interleaved 4*unit+type
    int u  = n >> 2, ty = n & 3;
    int g  = ty * 256 + u;
    const float* Wih = d ? Wihb : Wihf;
    const float* bi  = d ? bihb : bihf;
    const float* bh  = d ? bhhb : bhhf;
    const f32x4* e4 = (const f32x4*)(emb + c * EMBD);
    const f32x4* w4 = (const f32x4*)(Wih + g * EMBD);
    f32x4 a = {0.f, 0.f, 0.f, 0.f};
#pragma unroll
    for (int i = 0; i < 16; ++i) a += e4[i] * w4[i];
    xg[id] = bi[g] + bh[g] + a[0] + a[1] + a[2] + a[3];
  } else {                    // length-bucket sort, 256 threads
    int tid = threadIdx.x;
    if (tid < 16) { hist[tid] = 0; cnt[tid] = 0; }
    __syncthreads();
    for (int i = tid; i < N_WORDS; i += 256)
      atomicAdd(&hist[lengths[i] - 1], 1);
    __syncthreads();
    if (tid == 0) {
      int s = 0;
      for (int b = 0; b < 16; ++b) { base[b] = s; s += hist[b]; }
    }
    __syncthreads();
    for (int i = tid; i < N_WORDS; i += 256) {
      int b = lengths[i] - 1;
      int p = base[b] + atomicAdd(&cnt[b], 1);
      sorted[p] = i;
    }
  }
}

// ---------------- main fused BiLSTM kernel ----------------
// R15 = R14 with __syncthreads() restored -- single-variable A/B against R14's
// lgkm-only inline-asm barriers. R10/R14 both sat at ~450 regardless of MFMA
// chain count; the common delta vs R8 (362) is {xg, asm-barrier}. This round
// isolates the barrier. (Rule #18 family: hipcc treats inline-asm waitcnt +
// "memory" clobber as an opaque scheduling wall -- suspected codegen cost.)
// Everything else identical to R14: xg table (K=256), ping-pong weights,
// 4 MFMA chains, xg ping-pong prefetch, always-write epilogue.
__global__ __launch_bounds__(256, 2) void lstm_main(
    const int* __restrict__ char_ids, const int* __restrict__ lengths,
    const short* __restrict__ wsw, const float* __restrict__ xg,
    const int* __restrict__ sorted, float* __restrict__ out) {
  __shared__ __align__(16) short A[M_TILE * AROW];   // [word][h(256)+pad] 16.9 KB
  __shared__ __align__(16) int   charl[M_TILE * 16]; // 2 KB
  __shared__ __align__(8)  f32x2 c4[4 * 16 * 64];    // [wv][rt][lane] cell, 32 KB
  __shared__ int lenl[M_TILE];
  __shared__ int swl[M_TILE];

  const int tid  = threadIdx.x;
  const int lane = tid & 63;
  const int wv   = tid >> 6;            // 0..3
  const int quad = lane >> 4;
  const int colc = lane & 15;
  const int pb   = blockIdx.x;
  const int dir  = pb & 1;
  const int qb   = pb >> 1;
  const int tile = (qb & 1) ? (511 - (qb >> 1)) : (qb >> 1);

  if (tid < M_TILE) {
    int sw = sorted[tile * M_TILE + tid];
    swl[tid]  = sw;
    lenl[tid] = lengths[sw];
  }
  for (int i = tid; i < M_TILE * AROW / 2; i += 256) ((int*)A)[i] = 0;     // h=0
  for (int i = tid; i < 4 * 16 * 64; i += 256) c4[i] = (f32x2){0.f, 0.f}; // c=0
  __syncthreads();

  if (tid < 128) { // char ids for the tile (via sorted ids): 32 words x 16
    int w = tid >> 2, ch = tid & 3;
    ((i32x4*)charl)[tid] = ((const i32x4*)(char_ids + swl[w] * 16))[ch];
  }
  int Lmax = lenl[lane & 31];
  for (int o = 32; o; o >>= 1) { int v = __shfl_xor(Lmax, o, 64); Lmax = Lmax > v ? Lmax : v; }
  __syncthreads();  // charl ready

  // step-invariant lane constants (word dimension, per col-tile ct)
  int lenw0, lenw1, hadrb0, hadrb1, oadr0, oadr1;
  {
    int wl0 = colc, wl1 = 16 + colc;
    lenw0 = lenl[wl0];                  lenw1 = lenl[wl1];
    hadrb0 = wl0 * AROW + 64 * wv + quad;
    hadrb1 = wl1 * AROW + 64 * wv + quad;
    oadr0 = swl[wl0] * 512 + dir * 256 + 64 * wv + quad;
    oadr1 = swl[wl1] * 512 + dir * 256 + 64 * wv + quad;
  }
  const short* wp  = wsw + ((size_t)(dir * 64 + wv * 16)) * 4096 + lane * 8;
  const float* xga = xg + dir * (VOCABSZ * GATES);
  f32x2* cptr = c4 + wv * (16 * 64) + lane;   // + rt*64

  // xg row base for (word ct, step tt); clamped pos for dead steps is harmless
  auto ccof = [&](int tt, int len, int wl) -> int {
    int pos = (dir == 0) ? tt : (len - 1 - tt);
    pos = pos < 0 ? 0 : (pos > 15 ? 15 : pos);
    return charl[wl * 16 + pos] * GATES + 256 * wv + 4 * quad;
  };
  int cc0 = ccof(0, lenw0, colc), cc1 = ccof(0, lenw1, 16 + colc);

  __syncthreads();  // zeros visible

  // prologue loads: rt=0 weights + rt=0 xg for t=0
  bf16x8 wA[8], wB[8];
#pragma unroll
  for (int kk = 0; kk < 8; ++kk) wA[kk] = *(const bf16x8*)(wp + kk * 512);
  f32x4 xgA0 = *(const f32x4*)(xga + cc0);
  f32x4 xgA1 = *(const f32x4*)(xga + cc1);
  f32x4 xgB0, xgB1;

  bf16x8 hx_[2][8];  // B fragments (declared BEFORE wtile so the lambda captures)

  auto wtile = [&](int rt, bf16x8 (&wc)[8], bf16x8 (&wn)[8], int pre,
                   f32x4 xc0, f32x4 xc1, f32x4& xn0, f32x4& xn1,
                   int nb0, int nb1, int t) {
    // prefetch next tile's weights (pre=0 at rt=15 warms next step's rt0)
#pragma unroll
    for (int kk = 0; kk < 8; ++kk) wn[kk] = *(const bf16x8*)(wp + (pre * 8 + kk) * 512);
    // prefetch NEXT tile's xg (scattered gather -> full tile of cover)
    int rn = (rt + 1) & 15;
    xn0 = *(const f32x4*)(xga + nb0 + 16 * rn);
    xn1 = *(const f32x4*)(xga + nb1 + 16 * rn);
    f32x2 co2 = cptr[rt * 64];                 // LDS c, covered by the MFMA block
    f32x4 aL[2], aH[2];
#pragma unroll
    for (int ct = 0; ct < 2; ++ct) {
      aL[ct] = (f32x4){0.f, 0.f, 0.f, 0.f};
      aH[ct] = (f32x4){0.f, 0.f, 0.f, 0.f};
    }
#pragma unroll
    for (int kk = 0; kk < 4; ++kk)
#pragma unroll
      for (int ct = 0; ct < 2; ++ct) {  // 4 independent MFMA chains
        aL[ct] = __builtin_amdgcn_mfma_f32_16x16x32_bf16(wc[kk],     hx_[ct][kk],     aL[ct], 0, 0, 0);
        aH[ct] = __builtin_amdgcn_mfma_f32_16x16x32_bf16(wc[kk + 4], hx_[ct][kk + 4], aH[ct], 0, 0, 0);
      }
    f32x2 cnew;
#pragma unroll
    for (int ct = 0; ct < 2; ++ct) {
      f32x4 g4 = aL[ct] + aH[ct] + (ct ? xc1 : xc0);
      // lane-private epilogue: g4 = i,f,g,o of (unit 64wv+4rt+quad, word ct*16+colc)
      // always-write: masked words' h/c are don't-care (bounded, never output)
      float ig = fsig(g4[0]);
      float fg = fsig(g4[1]);
      float gg = ftanhf(g4[2]);
      float og = fsig(g4[3]);
      float c2 = fg * co2[ct] + ig * gg;
      float h2 = og * ftanhf(c2);
      cnew[ct] = c2;
      A[(ct ? hadrb1 : hadrb0) + 4 * rt] = tobf(h2);
      if (t == (ct ? lenw1 : lenw0) - 1)
        out[(ct ? oadr1 : oadr0) + 4 * rt] = h2;  // final h in fp32
    }
    cptr[rt * 64] = cnew;   // one ds_write_b64 (own slice, no hazard)
  };

#pragma unroll 1
  for (int t = 0; t < Lmax; ++t) {
#pragma unroll
    for (int ct = 0; ct < 2; ++ct)
#pragma unroll
      for (int kk = 0; kk < 8; ++kk)
        hx_[ct][kk] = *(const bf16x8*)(A + (ct * 16 + colc) * AROW + kk * 32 + quad * 8);
    // next step's xg bases (charl read-only; for rt=15's cross-step prefetch)
    int ccN0 = ccof(t + 1, lenw0, colc);
    int ccN1 = ccof(t + 1, lenw1, 16 + colc);

    __syncthreads();  // all waves snapshotted h -> safe to overwrite below

#pragma unroll 1
    for (int rt2 = 0; rt2 < 14; rt2 += 2) {
      wtile(rt2,     wA, wB, rt2 + 1, xgA0, xgA1, xgB0, xgB1, cc0, cc1, t);
      wtile(rt2 + 1, wB, wA, rt2 + 2, xgB0, xgB1, xgA0, xgA1, cc0, cc1, t);
    }
    wtile(14, wA, wB, 15, xgA0, xgA1, xgB0, xgB1, cc0,  cc1,  t);
    wtile(15, wB, wA, 0,  xgB0, xgB1, xgA0, xgA1, ccN0, ccN1, t);  // next step rt0
    cc0 = ccN0; cc1 = ccN1;

    __syncthreads();  // h/c writes visible before next step's reads
  }
}

// ---------------- launch ----------------
extern "C" void kernel_launch(void* const* d_in, const int* in_sizes, int n_in,
                              void* d_out, int out_size, void* d_ws, size_t ws_size,
                              hipStream_t stream) {
  const int*   char_ids = (const int*)d_in[0];
  const int*   lengths  = (const int*)d_in[1];
  const float* emb      = (const float*)d_in[2];
  const float* Wihf     = (const float*)d_in[3];
  const float* Whhf     = (const float*)d_in[4];
  const float* bihf     = (const float*)d_in[5];
  const float* bhhf     = (const float*)d_in[6];
  const float* Wihb     = (const float*)d_in[7];
  const float* Whhb     = (const float*)d_in[8];
  const float* bihb     = (const float*)d_in[9];
  const float* bhhb     = (const float*)d_in[10];

  char* ws = (char*)d_ws;
  short* wsw   = (short*)(ws + OFF_WSW);
  float* xg    = (float*)(ws + OFF_XG);
  int*   sortd = (int*)(ws + OFF_SORT);

  prep_all<<<1281, 256, 0, stream>>>(Wihf, Whhf, Wihb, Whhb, emb,
                                     bihf, bhhf, bihb, bhhb, lengths,
                                     wsw, xg, sortd);
  lstm_main<<<1024, 256, 0, stream>>>(char_ids, lengths, wsw, xg, sortd,
                                      (float*)d_out);
}